// Round 14
// baseline (94.288 us; speedup 1.0000x reference)
//
#include <hip/hip_runtime.h>
#include <hip/hip_bf16.h>

typedef __attribute__((ext_vector_type(8))) short bf16x8;
typedef __attribute__((ext_vector_type(4))) float f32x4;

#define WR_OFF   27557888   // Wr right after Xp (16*58*58*256*2B) in d_ws
// S (diag sums, 580608 floats = 2.32MB) lives in d_out scratch: written by
// diagsum, read by wsynth, then conv fully overwrites d_out. Stream-ordered.

#define BAND 24576          // one X band buffer: [slot4][row6][col64][16B]

// ---------------- per-level circulant diagonal sums -------------------------
// S[level][q][p][d][tap] = sum_{t<b} W[q*b+t][p*b+((t+d)&(b-1))][tap]
__global__ void diagsum_kernel(const float* __restrict__ W, float* __restrict__ S) {
    int tt = blockIdx.x * 256 + threadIdx.x;   // 64512 threads exactly
    int idx, n, lvlOff;
    if (tt < 32768)      { idx = 1; n = tt;          lvlOff = 0; }
    else if (tt < 49152) { idx = 2; n = tt - 32768;  lvlOff = 294912; }
    else if (tt < 57344) { idx = 3; n = tt - 49152;  lvlOff = 442368; }
    else if (tt < 61440) { idx = 4; n = tt - 57344;  lvlOff = 516096; }
    else if (tt < 63488) { idx = 5; n = tt - 61440;  lvlOff = 552960; }
    else                 { idx = 6; n = tt - 63488;  lvlOff = 571392; }
    int b = 1 << idx;
    int d = n & (b - 1);
    int qp = n >> idx;
    int p = qp & ((256 >> idx) - 1);
    int q = qp >> (8 - idx);
    float s[9];
    #pragma unroll
    for (int tp = 0; tp < 9; ++tp) s[tp] = 0.f;
    for (int ti = 0; ti < b; ++ti) {
        const float* wp = W + ((size_t)((q * b + ti) * 256 + p * b + ((ti + d) & (b - 1)))) * 9;
        #pragma unroll
        for (int tp = 0; tp < 9; ++tp) s[tp] += wp[tp];
    }
    float* o = S + (size_t)lvlOff + (size_t)n * 9;
    #pragma unroll
    for (int tp = 0; tp < 9; ++tp) o[tp] = s[tp];
}

// ------- fused: blocks [0,256) wsynth (needs only S); [256,3392) pad --------
// wsynth output layout = conv fragment layout: elem(tap,o,c) =
//   tap*65536 + (c>>5)*8192 + ((c>>3)&3)*2048 + o*8 + (c&7)
// pad: NCHW fp32 -> zero-padded NHWC bf16 [16][58][58][256] + border zeroing
__global__ void wsynth_pad_kernel(const float* __restrict__ W,
                                  const float* __restrict__ alphas,
                                  const float* __restrict__ gumbels,
                                  const float* __restrict__ S,
                                  __hip_bfloat16* __restrict__ Wr,
                                  const float* __restrict__ x,
                                  __hip_bfloat16* __restrict__ Xp) {
    __shared__ float t[64][65];
    if (blockIdx.x < 256) {
        // ---- wsynth half ----
        int tid = blockIdx.x * 256 + threadIdx.x;   // one thread per (o,i)
        int o = tid >> 8, i = tid & 255;

        float a[7]; float mx = -1e30f;
        for (int j = 0; j < 7; ++j) { a[j] = alphas[j] + 1.0e-4f * gumbels[j]; mx = fmaxf(mx, a[j]); }
        float s = 0.f;
        for (int j = 0; j < 7; ++j) { a[j] = __expf(a[j] - mx); s += a[j]; }
        float invs = 1.0f / s;
        for (int j = 0; j < 7; ++j) a[j] *= invs;

        float acc[9];
        const float* w0 = W + ((size_t)(o * 256 + i)) * 9;
        #pragma unroll
        for (int tp = 0; tp < 9; ++tp) acc[tp] = a[0] * w0[tp];

        const int lvlOff[7] = {0, 0, 294912, 442368, 516096, 552960, 571392};
        int dif = i - o;
        #pragma unroll
        for (int idx = 1; idx < 7; ++idx) {
            int b = 1 << idx;
            int q = o >> idx, p = i >> idx, d = dif & (b - 1);
            int n = ((q * (256 >> idx) + p) << idx) + d;
            const float* sp = S + lvlOff[idx] + (size_t)n * 9;
            float sc = a[idx] / (float)b;
            #pragma unroll
            for (int tp = 0; tp < 9; ++tp) acc[tp] += sc * sp[tp];
        }
        const size_t eb = (size_t)(i >> 5) * 8192 + ((i >> 3) & 3) * 2048 + o * 8 + (i & 7);
        #pragma unroll
        for (int tp = 0; tp < 9; ++tp)
            Wr[(size_t)tp * 65536 + eb] = __float2bfloat16(acc[tp]);
        return;
    }
    // ---- pad half ----
    int bl = blockIdx.x - 256;                 // 0..3135
    int bx = bl % 49, by = (bl / 49) % 4, bz = bl / 196;
    {   // border zeroing: 933888 elems over 802816 threads (1-2 each)
        int L = ((bz * 4 + by) * 49 + bx) * 256 + threadIdx.x;
        for (int e = L; e < 933888; e += 802816) {
            int c = e & 255;
            int pp = e >> 8;
            int b = pp / 228;
            int p = pp - b * 228;
            int y, xx;
            if (p < 58)       { y = 0;             xx = p; }
            else if (p < 116) { y = 57;            xx = p - 58; }
            else if (p < 172) { y = 1 + (p - 116); xx = 0; }
            else              { y = 1 + (p - 172); xx = 57; }
            Xp[((size_t)(b * 58 + y) * 58 + xx) * 256 + c] = __float2bfloat16(0.f);
        }
    }
    int p0 = bx * 64;               // pixel chunk within image (3136/64 = 49)
    int c0 = by * 64;               // channel chunk
    int b  = bz;                    // image
    int lane = threadIdx.x & 63;
    int grp  = threadIdx.x >> 6;    // 0..3

    const float* src = x + ((size_t)(b * 256 + c0)) * 3136 + p0;
    #pragma unroll
    for (int it = 0; it < 16; ++it) {
        int c = it * 4 + grp;
        t[c][lane] = src[(size_t)c * 3136 + lane];   // coalesced reads
    }
    __syncthreads();
    #pragma unroll
    for (int it = 0; it < 16; ++it) {
        int pl = it * 4 + grp;
        int P = p0 + pl;
        int y = P / 56, xx = P - y * 56;
        Xp[(((size_t)(b * 58 + y + 1)) * 58 + (xx + 1)) * 256 + c0 + lane] =
            __float2bfloat16(t[lane][pl]);           // coalesced 128B writes
    }
}

// ---- conv (exact R8 structure, best measured): 224x256 tile, W global->reg,
// ---- B-frags reg-dbuf, sched_barrier pin + setprio, counted vmcnt gates ----
__device__ __forceinline__ void gload16(const __hip_bfloat16* g, char* l) {
    __builtin_amdgcn_global_load_lds(
        (const __attribute__((address_space(1))) void*)g,
        (__attribute__((address_space(3))) void*)l, 16, 0, 0);
}

template<int N> __device__ __forceinline__ void gate() {
    if constexpr (N == 0)      asm volatile("s_waitcnt vmcnt(0)" ::: "memory");
    else if constexpr (N == 4) asm volatile("s_waitcnt vmcnt(4)" ::: "memory");
}

template<bool LAST>
__device__ __forceinline__ void chunk_pair(
    int cp, char* smem, const char* aBase,
    const int (&bOff)[7], const __hip_bfloat16* const (&xSrc)[3],
    int tid, bf16x8 (&afr)[2][4], bf16x8 (&bfv)[2][7], f32x4 (&acc)[4][7])
{
    #pragma unroll
    for (int u = 0; u < 2; ++u) {
        const int cc = 2 * cp + u;
        const char* xb = smem + u * BAND;          // cc&1 == u (2cp even)
        #pragma unroll
        for (int r = 0; r < 9; ++r) {
            const int cur = (u + r) & 1, nxt = cur ^ 1;
            // 0. stage next band right after the chunk barrier
            if (r == 0 && !(LAST && u == 1)) {
                char* d = smem + (u ^ 1) * BAND + tid * 16;
                #pragma unroll
                for (int it = 0; it < 3; ++it)
                    gload16(xSrc[it] + (cc + 1) * 32, d + it * 8192);
            }
            // 1. prefetch A-frags for next step (L2-resident Wr)
            if (!(LAST && u == 1 && r == 8)) {
                const int tapn = (r == 8) ? 0 : r + 1;
                const int aoff = tapn * 131072 + (cc + (r == 8 ? 1 : 0)) * 16384;
                #pragma unroll
                for (int nf = 0; nf < 4; ++nf)
                    afr[nxt][nf] = *(const bf16x8*)(aBase + aoff + nf * 256);
            }
            // 2. prefetch B-frags for next step (reg double-buffer)
            if (r < 8) {
                const int tapn = r + 1;
                const int timn = ((tapn / 3 - 1) * 64 + (tapn % 3 - 1)) * 16;
                #pragma unroll
                for (int mf = 0; mf < 7; ++mf)
                    bfv[nxt][mf] = *(const bf16x8*)(xb + bOff[mf] + timn);
            } else if (!(LAST && u == 1)) {
                const int timn = (-64 - 1) * 16;   // tap 0
                const char* xb2 = smem + (u ^ 1) * BAND;
                #pragma unroll
                for (int mf = 0; mf < 7; ++mf)
                    bfv[nxt][mf] = *(const bf16x8*)(xb2 + bOff[mf] + timn);
            }
            // pin: prefetches stay above the MFMA cluster
            __builtin_amdgcn_sched_barrier(0);
            // 3. MFMA cluster on current-step registers (28 MFMA)
            __builtin_amdgcn_s_setprio(1);
            #pragma unroll
            for (int nf = 0; nf < 4; ++nf)
                #pragma unroll
                for (int mf = 0; mf < 7; ++mf)
                    acc[nf][mf] = __builtin_amdgcn_mfma_f32_16x16x32_bf16(
                        afr[cur][nf], bfv[cur][mf], acc[nf][mf], 0, 0, 0);
            __builtin_amdgcn_s_setprio(0);
            // 4. chunk barrier at end of r==7: counted gate (band oldest in
            //    FIFO drains; newest A stays in flight); r==8 reads fresh band.
            if (r == 7 && !(LAST && u == 1)) {
                gate<4>();
                __builtin_amdgcn_s_barrier();
            }
        }
    }
}

__global__ __launch_bounds__(512, 2) void conv_kernel(
        const __hip_bfloat16* __restrict__ Xp,
        const __hip_bfloat16* __restrict__ Wr,
        float* __restrict__ out) {
    __shared__ char smem[2 * BAND];

    const int tid = threadIdx.x;
    const int w = tid >> 6, lane = tid & 63, l15 = lane & 15, q = lane >> 4;
    const int bid = blockIdx.x;            // 224 blocks: 14 per image, 4 rows
    const int bimg = bid / 14;
    const int y0 = (bid - bimg * 14) * 4;

    const int wn = (w & 3) << 6;           // wave och base (4 waves x 64)
    const int wm = (w >> 2) * 112;         // wave pixel base (2 waves x 112)

    // A-frag per-lane base (bytes into Wr): [tap][cc][q][och][8]
    const char* aBase = (const char*)Wr + q * 4096 + (wn + l15) * 16;

    // X band staging: 3 chunks/thread; chunk = tid + it*512 -> (slot, row, xcol)
    const __hip_bfloat16* xSrc[3];
    #pragma unroll
    for (int it = 0; it < 3; ++it) {
        int chunk = tid + it * 512;
        int slot = chunk / 384;
        int rem  = chunk - slot * 384;
        int row = rem >> 6, xcol = rem & 63;   // xcol>=58 reads in-bounds garbage (unused)
        xSrc[it] = Xp + (((size_t)(bimg * 58 + y0 + row)) * 58 + xcol) * 256 + slot * 8;
    }

    // B-frag read offsets (bytes); conflict-free [slot][row][16B] layout
    int bOff[7];
    #pragma unroll
    for (int mf = 0; mf < 7; ++mf) {
        int p = wm + mf * 16 + l15;            // local pixel 0..223
        int y = p / 56, xx = p - y * 56;
        bOff[mf] = q * 6144 + ((y + 1) * 64 + (xx + 1)) * 16;
    }

    f32x4 acc[4][7];
    #pragma unroll
    for (int a1 = 0; a1 < 4; ++a1)
        #pragma unroll
        for (int a2 = 0; a2 < 7; ++a2)
            acc[a1][a2] = (f32x4){0.f, 0.f, 0.f, 0.f};

    bf16x8 afr[2][4], bfv[2][7];

    // prologue: band 0 into buffer 0; A+B frags for step (tap0, cc0)
    {
        char* d = smem + tid * 16;
        #pragma unroll
        for (int it = 0; it < 3; ++it) gload16(xSrc[it], d + it * 8192);
    }
    #pragma unroll
    for (int nf = 0; nf < 4; ++nf)
        afr[0][nf] = *(const bf16x8*)(aBase + nf * 256);
    gate<0>();
    __builtin_amdgcn_s_barrier();
    {
        const int timm = (-64 - 1) * 16;       // tap 0: dy=-1, dx=-1
        #pragma unroll
        for (int mf = 0; mf < 7; ++mf)
            bfv[0][mf] = *(const bf16x8*)(smem + bOff[mf] + timm);
    }

    for (int cp = 0; cp < 3; ++cp)
        chunk_pair<false>(cp, smem, aBase, bOff, xSrc, tid, afr, bfv, acc);
    chunk_pair<true>(3, smem, aBase, bOff, xSrc, tid, afr, bfv, acc);

    // epilogue: och from (q,nf,rr), pixel from (wm,mf,l15); 64B runs
    const int nb = wn + q * 4;
    const size_t obB = (size_t)bimg * 256 * 3136;
    #pragma unroll
    for (int mf = 0; mf < 7; ++mf) {
        int pm = y0 * 56 + wm + mf * 16 + l15;
        #pragma unroll
        for (int nf = 0; nf < 4; ++nf) {
            #pragma unroll
            for (int rr = 0; rr < 4; ++rr)
                out[obB + (size_t)(nb + nf * 16 + rr) * 3136 + pm] = acc[nf][mf][rr];
        }
    }
}

extern "C" void kernel_launch(void* const* d_in, const int* in_sizes, int n_in,
                              void* d_out, int out_size, void* d_ws, size_t ws_size,
                              hipStream_t stream) {
    const float* x       = (const float*)d_in[0];
    const float* weight  = (const float*)d_in[1];
    const float* alphas  = (const float*)d_in[2];
    const float* gumbels = (const float*)d_in[3];
    float* out = (float*)d_out;

    __hip_bfloat16* Xp = (__hip_bfloat16*)d_ws;
    __hip_bfloat16* Wr = (__hip_bfloat16*)((char*)d_ws + WR_OFF);
    float*          S  = (float*)d_out;   // scratch; conv fully overwrites out

    hipLaunchKernelGGL(diagsum_kernel,    dim3(252),  dim3(256), 0, stream,
                       weight, S);
    hipLaunchKernelGGL(wsynth_pad_kernel, dim3(3392), dim3(256), 0, stream,
                       weight, alphas, gumbels, S, Wr, x, Xp);
    hipLaunchKernelGGL(conv_kernel,       dim3(224),  dim3(512), 0, stream,
                       Xp, Wr, out);
}

// Round 15
// 89.889 us; speedup vs baseline: 1.0489x; 1.0489x over previous
//
#include <hip/hip_runtime.h>
#include <hip/hip_bf16.h>

typedef __attribute__((ext_vector_type(8))) short bf16x8;
typedef __attribute__((ext_vector_type(4))) float f32x4;

#define WR_OFF   27557888   // Wr right after Xp (16*58*58*256*2B) in d_ws
// S (diag sums, 580608 floats = 2.32MB) lives in d_out scratch: written by
// prep (diagsum half), read by wsynth, then conv fully overwrites d_out.

#define BAND 24576          // one X band buffer: [slot4][row6][col64][16B]

// ------- fused prep: blocks [0,252) diagsum -> S(d_out); [252,3388) pad -----
// diagsum: S[level][q][p][d][tap] = sum_{t<b} W[q*b+t][p*b+((t+d)&(b-1))][tap]
// pad: NCHW fp32 -> zero-padded NHWC bf16 [16][58][58][256] + border zeroing
__global__ void prep_kernel(const float* __restrict__ W, float* __restrict__ S,
                            const float* __restrict__ x,
                            __hip_bfloat16* __restrict__ Xp) {
    __shared__ float t[64][65];
    if (blockIdx.x < 252) {
        int tt = blockIdx.x * 256 + threadIdx.x;   // 64512 threads exactly
        int idx, n, lvlOff;
        if (tt < 32768)      { idx = 1; n = tt;          lvlOff = 0; }
        else if (tt < 49152) { idx = 2; n = tt - 32768;  lvlOff = 294912; }
        else if (tt < 57344) { idx = 3; n = tt - 49152;  lvlOff = 442368; }
        else if (tt < 61440) { idx = 4; n = tt - 57344;  lvlOff = 516096; }
        else if (tt < 63488) { idx = 5; n = tt - 61440;  lvlOff = 552960; }
        else                 { idx = 6; n = tt - 63488;  lvlOff = 571392; }
        int b = 1 << idx;
        int d = n & (b - 1);
        int qp = n >> idx;
        int p = qp & ((256 >> idx) - 1);
        int q = qp >> (8 - idx);
        float s[9];
        #pragma unroll
        for (int tp = 0; tp < 9; ++tp) s[tp] = 0.f;
        for (int ti = 0; ti < b; ++ti) {
            const float* wp = W + ((size_t)((q * b + ti) * 256 + p * b + ((ti + d) & (b - 1)))) * 9;
            #pragma unroll
            for (int tp = 0; tp < 9; ++tp) s[tp] += wp[tp];
        }
        float* o = S + (size_t)lvlOff + (size_t)n * 9;
        #pragma unroll
        for (int tp = 0; tp < 9; ++tp) o[tp] = s[tp];
        return;
    }
    // ---- pad half ----
    int bl = blockIdx.x - 252;                 // 0..3135
    int bx = bl % 49, by = (bl / 49) % 4, bz = bl / 196;
    {   // border zeroing: 933888 elems over 802816 threads (1-2 each)
        int L = ((bz * 4 + by) * 49 + bx) * 256 + threadIdx.x;
        for (int e = L; e < 933888; e += 802816) {
            int c = e & 255;
            int pp = e >> 8;
            int b = pp / 228;
            int p = pp - b * 228;
            int y, xx;
            if (p < 58)       { y = 0;             xx = p; }
            else if (p < 116) { y = 57;            xx = p - 58; }
            else if (p < 172) { y = 1 + (p - 116); xx = 0; }
            else              { y = 1 + (p - 172); xx = 57; }
            Xp[((size_t)(b * 58 + y) * 58 + xx) * 256 + c] = __float2bfloat16(0.f);
        }
    }
    int p0 = bx * 64;               // pixel chunk within image (3136/64 = 49)
    int c0 = by * 64;               // channel chunk
    int b  = bz;                    // image
    int lane = threadIdx.x & 63;
    int grp  = threadIdx.x >> 6;    // 0..3

    const float* src = x + ((size_t)(b * 256 + c0)) * 3136 + p0;
    #pragma unroll
    for (int it = 0; it < 16; ++it) {
        int c = it * 4 + grp;
        t[c][lane] = src[(size_t)c * 3136 + lane];   // coalesced reads
    }
    __syncthreads();
    #pragma unroll
    for (int it = 0; it < 16; ++it) {
        int pl = it * 4 + grp;
        int P = p0 + pl;
        int y = P / 56, xx = P - y * 56;
        Xp[(((size_t)(b * 58 + y + 1)) * 58 + (xx + 1)) * 256 + c0 + lane] =
            __float2bfloat16(t[lane][pl]);           // coalesced 128B writes
    }
}

// ---------------- weight synthesis: softmax + gather of diag sums -----------
// Output layout = conv fragment layout: elem(tap,o,c) =
//   tap*65536 + (c>>5)*8192 + ((c>>3)&3)*2048 + o*8 + (c&7)
__global__ void wsynth_kernel(const float* __restrict__ W,
                              const float* __restrict__ alphas,
                              const float* __restrict__ gumbels,
                              const float* __restrict__ S,
                              __hip_bfloat16* __restrict__ Wr) {
    int tid = blockIdx.x * 256 + threadIdx.x;   // 65536 threads: one per (o,i)
    int o = tid >> 8, i = tid & 255;

    float a[7]; float mx = -1e30f;
    for (int j = 0; j < 7; ++j) { a[j] = alphas[j] + 1.0e-4f * gumbels[j]; mx = fmaxf(mx, a[j]); }
    float s = 0.f;
    for (int j = 0; j < 7; ++j) { a[j] = __expf(a[j] - mx); s += a[j]; }
    float invs = 1.0f / s;
    for (int j = 0; j < 7; ++j) a[j] *= invs;

    float acc[9];
    const float* w0 = W + ((size_t)(o * 256 + i)) * 9;
    #pragma unroll
    for (int t = 0; t < 9; ++t) acc[t] = a[0] * w0[t];

    const int lvlOff[7] = {0, 0, 294912, 442368, 516096, 552960, 571392};
    int dif = i - o;
    #pragma unroll
    for (int idx = 1; idx < 7; ++idx) {
        int b = 1 << idx;
        int q = o >> idx, p = i >> idx, d = dif & (b - 1);
        int n = ((q * (256 >> idx) + p) << idx) + d;
        const float* sp = S + lvlOff[idx] + (size_t)n * 9;
        float sc = a[idx] / (float)b;
        #pragma unroll
        for (int tp = 0; tp < 9; ++tp) acc[tp] += sc * sp[tp];
    }
    const size_t eb = (size_t)(i >> 5) * 8192 + ((i >> 3) & 3) * 2048 + o * 8 + (i & 7);
    #pragma unroll
    for (int tp = 0; tp < 9; ++tp)
        Wr[(size_t)tp * 65536 + eb] = __float2bfloat16(acc[tp]);
}

// ---- conv (R8 structure, best measured): 224x256 tile, W global->reg,
// ---- B-frags reg-dbuf, sched_barrier pin + setprio, counted vmcnt gates ----
__device__ __forceinline__ void gload16(const __hip_bfloat16* g, char* l) {
    __builtin_amdgcn_global_load_lds(
        (const __attribute__((address_space(1))) void*)g,
        (__attribute__((address_space(3))) void*)l, 16, 0, 0);
}

template<int N> __device__ __forceinline__ void gate() {
    if constexpr (N == 0)      asm volatile("s_waitcnt vmcnt(0)" ::: "memory");
    else if constexpr (N == 4) asm volatile("s_waitcnt vmcnt(4)" ::: "memory");
}

template<bool LAST>
__device__ __forceinline__ void chunk_pair(
    int cp, char* smem, const char* aBase,
    const int (&bOff)[7], const __hip_bfloat16* const (&xSrc)[3],
    int tid, bf16x8 (&afr)[2][4], bf16x8 (&bfv)[2][7], f32x4 (&acc)[4][7])
{
    #pragma unroll
    for (int u = 0; u < 2; ++u) {
        const int cc = 2 * cp + u;
        const char* xb = smem + u * BAND;          // cc&1 == u (2cp even)
        #pragma unroll
        for (int r = 0; r < 9; ++r) {
            const int cur = (u + r) & 1, nxt = cur ^ 1;
            // 0. stage next band right after the chunk barrier
            if (r == 0 && !(LAST && u == 1)) {
                char* d = smem + (u ^ 1) * BAND + tid * 16;
                #pragma unroll
                for (int it = 0; it < 3; ++it)
                    gload16(xSrc[it] + (cc + 1) * 32, d + it * 8192);
            }
            // 1. prefetch A-frags for next step (L2-resident Wr)
            if (!(LAST && u == 1 && r == 8)) {
                const int tapn = (r == 8) ? 0 : r + 1;
                const int aoff = tapn * 131072 + (cc + (r == 8 ? 1 : 0)) * 16384;
                #pragma unroll
                for (int nf = 0; nf < 4; ++nf)
                    afr[nxt][nf] = *(const bf16x8*)(aBase + aoff + nf * 256);
            }
            // 2. prefetch B-frags for next step (reg double-buffer)
            if (r < 8) {
                const int tapn = r + 1;
                const int timn = ((tapn / 3 - 1) * 64 + (tapn % 3 - 1)) * 16;
                #pragma unroll
                for (int mf = 0; mf < 7; ++mf)
                    bfv[nxt][mf] = *(const bf16x8*)(xb + bOff[mf] + timn);
            } else if (!(LAST && u == 1)) {
                const int timn = (-64 - 1) * 16;   // tap 0
                const char* xb2 = smem + (u ^ 1) * BAND;
                #pragma unroll
                for (int mf = 0; mf < 7; ++mf)
                    bfv[nxt][mf] = *(const bf16x8*)(xb2 + bOff[mf] + timn);
            }
            // pin: prefetches stay above the MFMA cluster
            __builtin_amdgcn_sched_barrier(0);
            // 3. MFMA cluster on current-step registers (28 MFMA)
            __builtin_amdgcn_s_setprio(1);
            #pragma unroll
            for (int nf = 0; nf < 4; ++nf)
                #pragma unroll
                for (int mf = 0; mf < 7; ++mf)
                    acc[nf][mf] = __builtin_amdgcn_mfma_f32_16x16x32_bf16(
                        afr[cur][nf], bfv[cur][mf], acc[nf][mf], 0, 0, 0);
            __builtin_amdgcn_s_setprio(0);
            // 4. chunk barrier at end of r==7: counted gate (band oldest in
            //    FIFO drains; newest A stays in flight); r==8 reads fresh band.
            if (r == 7 && !(LAST && u == 1)) {
                gate<4>();
                __builtin_amdgcn_s_barrier();
            }
        }
    }
}

__global__ __launch_bounds__(512, 2) void conv_kernel(
        const __hip_bfloat16* __restrict__ Xp,
        const __hip_bfloat16* __restrict__ Wr,
        float* __restrict__ out) {
    __shared__ char smem[2 * BAND];

    const int tid = threadIdx.x;
    const int w = tid >> 6, lane = tid & 63, l15 = lane & 15, q = lane >> 4;
    const int bid = blockIdx.x;            // 224 blocks: 14 per image, 4 rows
    const int bimg = bid / 14;
    const int y0 = (bid - bimg * 14) * 4;

    const int wn = (w & 3) << 6;           // wave och base (4 waves x 64)
    const int wm = (w >> 2) * 112;         // wave pixel base (2 waves x 112)

    // A-frag per-lane base (bytes into Wr): [tap][cc][q][och][8]
    const char* aBase = (const char*)Wr + q * 4096 + (wn + l15) * 16;

    // X band staging: 3 chunks/thread; chunk = tid + it*512 -> (slot, row, xcol)
    const __hip_bfloat16* xSrc[3];
    #pragma unroll
    for (int it = 0; it < 3; ++it) {
        int chunk = tid + it * 512;
        int slot = chunk / 384;
        int rem  = chunk - slot * 384;
        int row = rem >> 6, xcol = rem & 63;   // xcol>=58 reads in-bounds garbage (unused)
        xSrc[it] = Xp + (((size_t)(bimg * 58 + y0 + row)) * 58 + xcol) * 256 + slot * 8;
    }

    // B-frag read offsets (bytes); conflict-free [slot][row][16B] layout
    int bOff[7];
    #pragma unroll
    for (int mf = 0; mf < 7; ++mf) {
        int p = wm + mf * 16 + l15;            // local pixel 0..223
        int y = p / 56, xx = p - y * 56;
        bOff[mf] = q * 6144 + ((y + 1) * 64 + (xx + 1)) * 16;
    }

    f32x4 acc[4][7];
    #pragma unroll
    for (int a1 = 0; a1 < 4; ++a1)
        #pragma unroll
        for (int a2 = 0; a2 < 7; ++a2)
            acc[a1][a2] = (f32x4){0.f, 0.f, 0.f, 0.f};

    bf16x8 afr[2][4], bfv[2][7];

    // prologue: band 0 into buffer 0; A+B frags for step (tap0, cc0)
    {
        char* d = smem + tid * 16;
        #pragma unroll
        for (int it = 0; it < 3; ++it) gload16(xSrc[it], d + it * 8192);
    }
    #pragma unroll
    for (int nf = 0; nf < 4; ++nf)
        afr[0][nf] = *(const bf16x8*)(aBase + nf * 256);
    gate<0>();
    __builtin_amdgcn_s_barrier();
    {
        const int timm = (-64 - 1) * 16;       // tap 0: dy=-1, dx=-1
        #pragma unroll
        for (int mf = 0; mf < 7; ++mf)
            bfv[0][mf] = *(const bf16x8*)(smem + bOff[mf] + timm);
    }

    for (int cp = 0; cp < 3; ++cp)
        chunk_pair<false>(cp, smem, aBase, bOff, xSrc, tid, afr, bfv, acc);
    chunk_pair<true>(3, smem, aBase, bOff, xSrc, tid, afr, bfv, acc);

    // epilogue: och from (q,nf,rr), pixel from (wm,mf,l15); 64B runs
    const int nb = wn + q * 4;
    const size_t obB = (size_t)bimg * 256 * 3136;
    #pragma unroll
    for (int mf = 0; mf < 7; ++mf) {
        int pm = y0 * 56 + wm + mf * 16 + l15;
        #pragma unroll
        for (int nf = 0; nf < 4; ++nf) {
            #pragma unroll
            for (int rr = 0; rr < 4; ++rr)
                out[obB + (size_t)(nb + nf * 16 + rr) * 3136 + pm] = acc[nf][mf][rr];
        }
    }
}

extern "C" void kernel_launch(void* const* d_in, const int* in_sizes, int n_in,
                              void* d_out, int out_size, void* d_ws, size_t ws_size,
                              hipStream_t stream) {
    const float* x       = (const float*)d_in[0];
    const float* weight  = (const float*)d_in[1];
    const float* alphas  = (const float*)d_in[2];
    const float* gumbels = (const float*)d_in[3];
    float* out = (float*)d_out;

    __hip_bfloat16* Xp = (__hip_bfloat16*)d_ws;
    __hip_bfloat16* Wr = (__hip_bfloat16*)((char*)d_ws + WR_OFF);
    float*          S  = (float*)d_out;   // scratch; conv fully overwrites out

    hipLaunchKernelGGL(prep_kernel,   dim3(3388), dim3(256), 0, stream,
                       weight, S, x, Xp);
    hipLaunchKernelGGL(wsynth_kernel, dim3(256),  dim3(256), 0, stream,
                       weight, alphas, gumbels, S, Wr);
    hipLaunchKernelGGL(conv_kernel,   dim3(224),  dim3(512), 0, stream,
                       Xp, Wr, out);
}